// Round 1
// 202.367 us; speedup vs baseline: 1.0181x; 1.0181x over previous
//
#include <hip/hip_runtime.h>
#include <hip/hip_bf16.h>
#include <cstdint>

#define H 1024
#define BSZ 4
#define LSEQ 2048
#define M_TOT (BSZ*LSEQ)   // 8192
#define NCH 32             // L-chunks for the delta scan
#define LCH (LSEQ/NCH)     // 64

typedef __attribute__((ext_vector_type(4))) float  f32x4;
typedef __attribute__((ext_vector_type(2))) float  f32x2;
typedef __attribute__((ext_vector_type(8))) __bf16 bf16x8;
typedef __attribute__((ext_vector_type(4))) __bf16 bf16x4;
typedef __attribute__((ext_vector_type(2))) __bf16 bf16x2;

typedef __attribute__((address_space(1))) unsigned int as1_u32;
typedef __attribute__((address_space(3))) unsigned int as3_u32;

__device__ __forceinline__ void gld_lds16(const void* g, const void* l) {
    as1_u32* gp = reinterpret_cast<as1_u32*>((uintptr_t)g);
    as3_u32* lp = reinterpret_cast<as3_u32*>((uint32_t)(uintptr_t)l);
    __builtin_amdgcn_global_load_lds(gp, lp, 16, 0, 0);
}

// fast softplus: stable, native exp/log (v_exp_f32/v_log_f32), ~8 instrs
__device__ __forceinline__ float softplus_fast(float f) {
    return fmaxf(f, 0.f) + __logf(1.f + __expf(-fabsf(f)));
}

// ---------------- small GEMM (Wfuse = Wd @ Wp1): unchanged 128x128 ----------
template<int KT, int MODE>
__global__ __launch_bounds__(256, 3) void gemm_bt(
    const __bf16* __restrict__ A,
    const __bf16* __restrict__ B,
    __bf16* __restrict__ O0,
    __bf16* __restrict__ O2,
    const __bf16* __restrict__ xb,
    const float* __restrict__ bias,
    float* __restrict__ pD,
    float* __restrict__ pUp,
    float* __restrict__ pCp)
{
    constexpr int K = KT * 32;
    __shared__ __align__(16) __bf16 lds[17408];

    const int tid  = threadIdx.x;
    const int lane = tid & 63;
    const int wid  = tid >> 6;
    const int wr   = (wid >> 1) * 64;
    const int wc   = (wid & 1) * 64;
    const int l15  = lane & 15;
    const int quad = lane >> 4;

    const int row0 = blockIdx.y * 128;
    const int col0 = blockIdx.x * 128;

    const int srow = lane >> 2;
    const int soct = (lane & 3) ^ ((lane >> 3) & 3);
    const __bf16* ag0 = A + (size_t)(row0 + (wid    )*16 + srow) * K + soct*8;
    const __bf16* ag1 = A + (size_t)(row0 + (wid + 4)*16 + srow) * K + soct*8;
    const __bf16* bg0 = B + (size_t)(col0 + (wid    )*16 + srow) * K + soct*8;
    const __bf16* bg1 = B + (size_t)(col0 + (wid + 4)*16 + srow) * K + soct*8;
    const int lA0 = (wid    )*512;
    const int lA1 = (wid + 4)*512;
    const int lB0 = 4096 + (wid    )*512;
    const int lB1 = 4096 + (wid + 4)*512;

    const int sw = (l15 >> 1) & 3;
    int aoff[4], boff[4];
#pragma unroll
    for (int i = 0; i < 4; ++i) {
        aoff[i] =        ((wr + i*16 + l15) * 4 + (quad ^ sw)) * 8;
        boff[i] = 4096 + ((wc + i*16 + l15) * 4 + (quad ^ sw)) * 8;
    }

    f32x4 acc[4][4] = {};

    auto stage = [&](int buf) {
        __bf16* base = lds + buf * 8192;
        gld_lds16(ag0, base + lA0);
        gld_lds16(ag1, base + lA1);
        gld_lds16(bg0, base + lB0);
        gld_lds16(bg1, base + lB1);
        ag0 += 32; ag1 += 32; bg0 += 32; bg1 += 32;
    };
    auto compute = [&](int buf) {
        const __bf16* base = lds + buf * 8192;
        bf16x8 af[4], bf[4];
#pragma unroll
        for (int i = 0; i < 4; ++i) af[i] = *(const bf16x8*)(base + aoff[i]);
#pragma unroll
        for (int j = 0; j < 4; ++j) bf[j] = *(const bf16x8*)(base + boff[j]);
#pragma unroll
        for (int i = 0; i < 4; ++i)
#pragma unroll
            for (int j = 0; j < 4; ++j)
                acc[i][j] = __builtin_amdgcn_mfma_f32_16x16x32_bf16(
                    af[i], bf[j], acc[i][j], 0, 0, 0);
    };

    stage(0);
#pragma unroll 2
    for (int kt = 0; kt < KT; ++kt) {
        __syncthreads();
        if (kt + 1 < KT) stage((kt + 1) & 1);
        compute(kt & 1);
    }

    const int colb = (col0 & 1023) + wc + l15;
    const int rowb = row0 + wr + quad*4;

    if (MODE == 0) {
#pragma unroll
        for (int i = 0; i < 4; ++i)
#pragma unroll
            for (int j = 0; j < 4; ++j) {
                const int col = colb + j*16;
#pragma unroll
                for (int r = 0; r < 4; ++r)
                    O0[(size_t)(rowb + i*16 + r) * H + col] = (__bf16)acc[i][j][r];
            }
    }
    (void)xb; (void)bias; (void)pD; (void)pUp; (void)pCp; (void)O2;
}

// ---------------- BIG GEMM: 256x256 tile, 8-wave, 8-phase, counted vmcnt ----
// C[M,N] = A[M,K] @ B[N,K]^T, bf16 in, K=1024, BK=64, 2 K-tiles/iteration.
// LDS: 2 dbuf x (A[256][64] + B[256][64]) bf16 = 128 KiB, 1 block/CU.
// Staging: pre-swizzled global source (granule pos = logical ^ (row&7)),
//   linear global_load_lds dest; ds_read applies the same XOR -> uniform
//   8 lanes per 16B granule position = conflict-free ds_read_b128.
// Waits: s_waitcnt vmcnt(2) at phases 1 and 5 only (2 loads/wave/phase;
//   retires exactly the 4 half-tiles of the tile about to be consumed).
// Epilogue: seg0 softplus+store+pD chunk sums; seg1 C-tile->LDS reduce ->
//   pUp/pCp[64][1024] (formats unchanged); seg2 plain store.

#define BAR()    asm volatile("s_barrier" ::: "memory")
#define WAITV2() asm volatile("s_waitcnt vmcnt(2)" ::: "memory")

#define STAGE_A(d, h, kt) do {                                               \
    const __bf16* g_ = Asrc + (size_t)((h)*128) * H + (kt)*64;               \
    const __bf16* l_ = lds + (d)*32768 + ((h)*128)*64 + lwave;               \
    gld_lds16(g_,          l_);                                              \
    gld_lds16(g_ + 64*H,   l_ + 64*64);                                      \
} while(0)

#define STAGE_B(d, h, kt) do {                                               \
    const __bf16* g_ = Bsrc + (size_t)((h)*128) * H + (kt)*64;               \
    const __bf16* l_ = lds + (d)*32768 + 16384 + ((h)*128)*64 + lwave;       \
    gld_lds16(g_,          l_);                                              \
    gld_lds16(g_ + 64*H,   l_ + 64*64);                                      \
} while(0)

#define RD_A(d, mh) do {                                                     \
    const __bf16* base_ = lds + (d)*32768;                                   \
    _Pragma("unroll")                                                        \
    for (int ii = 0; ii < 4; ++ii) {                                         \
        af[ii][0] = *(const bf16x8*)(base_ + aoff[(mh)*4 + ii]);             \
        af[ii][1] = *(const bf16x8*)(base_ + (aoff[(mh)*4 + ii] ^ 32));      \
    }                                                                        \
} while(0)

#define RD_B(d, nh) do {                                                     \
    const __bf16* base_ = lds + (d)*32768;                                   \
    _Pragma("unroll")                                                        \
    for (int jj = 0; jj < 2; ++jj) {                                         \
        bf[(nh)*2+jj][0] = *(const bf16x8*)(base_ + boff[(nh)*2 + jj]);      \
        bf[(nh)*2+jj][1] = *(const bf16x8*)(base_ + (boff[(nh)*2 + jj] ^ 32)); \
    }                                                                        \
} while(0)

#define MM(mh, nh) do {                                                      \
    __builtin_amdgcn_s_setprio(1);                                           \
    _Pragma("unroll")                                                        \
    for (int ii = 0; ii < 4; ++ii)                                           \
    _Pragma("unroll")                                                        \
    for (int jj = 0; jj < 2; ++jj)                                           \
    _Pragma("unroll")                                                        \
    for (int kk = 0; kk < 2; ++kk)                                           \
        acc[(mh)*4+ii][(nh)*2+jj] = __builtin_amdgcn_mfma_f32_16x16x32_bf16( \
            af[ii][kk], bf[(nh)*2+jj][kk], acc[(mh)*4+ii][(nh)*2+jj], 0,0,0);\
    __builtin_amdgcn_s_setprio(0);                                           \
} while(0)

__global__ __launch_bounds__(512, 2) void gemm256(
    const __bf16* __restrict__ A,
    const __bf16* __restrict__ B,
    __bf16* __restrict__ O0,
    __bf16* __restrict__ O2,
    const __bf16* __restrict__ xb,
    const float* __restrict__ bias,
    float* __restrict__ pD,
    float* __restrict__ pUp,
    float* __restrict__ pCp)
{
    __shared__ __align__(16) __bf16 lds[65536];   // 128 KiB

    const int tid  = threadIdx.x;
    const int lane = tid & 63;
    const int wid  = tid >> 6;
    const int l15  = lane & 15;
    const int quad = lane >> 4;
    const int wrv  = (wid >> 2) * 128;   // 2 M-waves
    const int wcv  = (wid & 3) * 64;     // 4 N-waves

    // XCD-bijective swizzle: 384 blocks, 384 % 8 == 0
    const int bid = blockIdx.x;
    const int swz = (bid & 7) * 48 + (bid >> 3);
    const int bx = swz % 12;
    const int by = swz / 12;
    const int row0 = by * 256;
    const int col0 = bx * 256;

    // staging source (pre-swizzled granule), per-lane
    const int lg = (tid & 7) ^ ((tid >> 3) & 7);
    const __bf16* Asrc = A + (size_t)(row0 + (tid >> 3)) * H + lg * 8;
    const __bf16* Bsrc = B + (size_t)(col0 + (tid >> 3)) * H + lg * 8;
    const int lwave = wid * 8 * 64;      // wave-uniform LDS base (elements)

    // ds_read element offsets (kk=0); kk=1 = ^32
    int aoff[8], boff[4];
#pragma unroll
    for (int i = 0; i < 8; ++i)
        aoff[i] = (wrv + i*16 + l15)*64 + ((quad ^ (l15 & 7)) << 3);
#pragma unroll
    for (int j = 0; j < 4; ++j)
        boff[j] = 16384 + (wcv + j*16 + l15)*64 + ((quad ^ (l15 & 7)) << 3);

    f32x4 acc[8][4] = {};
    bf16x8 af[4][2], bf[4][2];

    // prologue: tile0 (dbuf0, 4 halves) + tile1.A.h0 (dbuf1) -> 10 outstanding
    STAGE_A(0,0,0); STAGE_A(0,1,0); STAGE_B(0,0,0); STAGE_B(0,1,0);
    STAGE_A(1,0,1);

#pragma unroll 1
    for (int it = 0; it < 8; ++it) {
        const int t1 = 2*it + 1;
        const int t2 = (it < 7) ? 2*it + 2 : 15;   // clamp: redundant re-read
        const int t3 = (it < 7) ? 2*it + 3 : 15;
        // ---- tile t0 = 2*it from dbuf0 ----
        WAITV2(); BAR();                            // t0 fully staged
        RD_A(0,0); RD_B(0,0);
        STAGE_A(1,1,t1);
        BAR(); MM(0,0); BAR();
        RD_B(0,1);
        STAGE_B(1,0,t1);
        BAR(); MM(0,1); BAR();
        RD_A(0,1);
        STAGE_B(1,1,t1);
        BAR(); MM(1,0); BAR();
        STAGE_A(0,0,t2);
        BAR(); MM(1,1); BAR();
        // ---- tile t1 from dbuf1 ----
        WAITV2(); BAR();                            // t1 fully staged
        RD_A(1,0); RD_B(1,0);
        STAGE_A(0,1,t2);
        BAR(); MM(0,0); BAR();
        RD_B(1,1);
        STAGE_B(0,0,t2);
        BAR(); MM(0,1); BAR();
        RD_A(1,1);
        STAGE_B(0,1,t2);
        BAR(); MM(1,0); BAR();
        STAGE_A(1,0,t3);
        BAR(); MM(1,1); BAR();
    }
    asm volatile("s_waitcnt vmcnt(0)" ::: "memory"); // drain before LDS reuse
    __syncthreads();

    // ---------------- epilogue ----------------
    const int seg   = col0 >> 10;
    const int cbase = col0 & 1023;
    const int colb  = cbase + wcv + l15;
    const int rowb  = row0 + wrv + quad*4;

    if (seg == 0) {
        // delta: bias + softplus + store + per-64-row-chunk col sums
        const int chunkb = (row0 + wrv) >> 6;
#pragma unroll
        for (int j = 0; j < 4; ++j) {
            const int col = colb + j*16;
            const float bv = bias[col];
#pragma unroll
            for (int ih = 0; ih < 2; ++ih) {
                float s = 0.f;
#pragma unroll
                for (int ii = 0; ii < 4; ++ii) {
                    const int i = ih*4 + ii;
#pragma unroll
                    for (int r = 0; r < 4; ++r) {
                        float f = softplus_fast(acc[i][j][r] + bv);
                        O0[(size_t)(rowb + i*16 + r) * H + col] = (__bf16)f;
                        s += f;
                    }
                }
                s += __shfl_down(s, 32); s += __shfl_down(s, 16);
                if (quad == 0) pD[(chunkb + ih)*H + col] = s;  // single writer
            }
        }
    } else if (seg == 2) {
        // residual: plain store
#pragma unroll
        for (int i = 0; i < 8; ++i)
#pragma unroll
            for (int j = 0; j < 4; ++j) {
                const int col = colb + j*16;
#pragma unroll
                for (int r = 0; r < 4; ++r)
                    O2[(size_t)(rowb + i*16 + r) * H + col] = (__bf16)acc[i][j][r];
            }
    } else {
        // Cs: 256x256 tile -> LDS (granule-XOR), coalesced reduce with xb,
        // cross-group reduce -> pUp/pCp[64][1024] (per-128-row partials).
#pragma unroll
        for (int i = 0; i < 8; ++i)
#pragma unroll
            for (int j = 0; j < 4; ++j) {
                const int lcol = wcv + j*16 + l15;
#pragma unroll
                for (int r = 0; r < 4; ++r) {
                    const int lrow = wrv + i*16 + quad*4 + r;
                    lds[lrow*256 + (((lcol>>3) ^ ((lrow>>2)&7))<<3) + (lcol&7)]
                        = (__bf16)acc[i][j][r];
                }
            }
        __syncthreads();
        const int g = tid >> 5, oct = tid & 31;
        const int gc0 = cbase + oct*8;
        float su[8] = {}, sc[8] = {};
#pragma unroll
        for (int rr = 0; rr < 16; ++rr) {
            const int lrow = g*16 + rr;
            bf16x8 cv = *(const bf16x8*)(lds + lrow*256 +
                                         ((oct ^ ((lrow>>2)&7)) << 3));
            bf16x8 xv = *(const bf16x8*)(xb + (size_t)(row0 + lrow)*H + gc0);
#pragma unroll
            for (int q = 0; q < 8; ++q) {
                float c = (float)cv[q];
                su[q] += (float)xv[q] * c;
                sc[q] += c;
            }
        }
        float* pf = reinterpret_cast<float*>(lds);
        __syncthreads();
#pragma unroll
        for (int q = 0; q < 8; ++q) {
            pf[g*256 + oct*8 + q]        = su[q];
            pf[4096 + g*256 + oct*8 + q] = sc[q];
        }
        __syncthreads();
        const int col = tid & 255;
        const int sel = tid >> 8;
#pragma unroll
        for (int rb2 = 0; rb2 < 2; ++rb2) {
            float s = 0.f;
#pragma unroll
            for (int g2 = 0; g2 < 8; ++g2)
                s += pf[sel*4096 + (rb2*8 + g2)*256 + col];
            float* dst = sel ? pCp : pUp;
            dst[(size_t)((row0 >> 7) + rb2)*H + cbase + col] = s;
        }
    }
}

// ---- cast f32->bf16: x; pack W_proj segs {Cs,res}; Wd; transpose Wp1 -------
#define XB 8192
#define PB 2048
#define DB 1024
#define TB 256
__global__ void cast_kernel(const float* __restrict__ x,
                            const float* __restrict__ Wp,
                            const float* __restrict__ Wd,
                            __bf16* __restrict__ xb,
                            __bf16* __restrict__ Wpb,
                            __bf16* __restrict__ Wdb,
                            __bf16* __restrict__ Wp1T)
{
    __shared__ __bf16 tlds[64*65];
    const int t = threadIdx.x;
    const int bidx = blockIdx.x;

    if (bidx < XB + PB + DB) {
        const f32x4* src; __bf16* dst; int si, di;
        if (bidx < XB) {
            int i = bidx*256 + t;
            src = (const f32x4*)x;  si = i; dst = xb;  di = i;
        } else if (bidx < XB + PB) {
            int j = (bidx - XB)*256 + t;
            int row = j >> 8, cf = j & 255;
            src = (const f32x4*)Wp; si = (2048 + row)*256 + cf;
            dst = Wpb; di = (1024 + row)*256 + cf;
        } else {
            int j = (bidx - XB - PB)*256 + t;
            src = (const f32x4*)Wd; si = j; dst = Wdb; di = j;
        }
        f32x4 v = src[si];
        bf16x4 o = { (__bf16)v[0], (__bf16)v[1], (__bf16)v[2], (__bf16)v[3] };
        *(bf16x4*)(dst + (size_t)di*4) = o;
    } else {
        int tt = bidx - (XB + PB + DB);
        int ty = tt >> 4, tx = tt & 15;
        int rb = t >> 4, cb = t & 15;
#pragma unroll
        for (int rr = 0; rr < 4; ++rr) {
            int row = rb*4 + rr;
            f32x4 v = *(const f32x4*)(Wp + (size_t)(ty*64 + row)*1024 + tx*64 + cb*4);
#pragma unroll
            for (int q = 0; q < 4; ++q)
                tlds[row*65 + cb*4 + q] = (__bf16)v[q];
        }
        __syncthreads();
#pragma unroll
        for (int rr = 0; rr < 4; ++rr) {
            int kk = rb*4 + rr;
            bf16x4 o = { tlds[(cb*4+0)*65 + kk], tlds[(cb*4+1)*65 + kk],
                         tlds[(cb*4+2)*65 + kk], tlds[(cb*4+3)*65 + kk] };
            *(bf16x4*)(Wp1T + (size_t)(tx*64 + kk)*1024 + ty*64 + cb*4) = o;
        }
    }
}

// ---- final: inline chunk-prefix + partial-sum gather + elementwise combine --
__global__ void final_kernel(const __bf16* __restrict__ delta,
                             const __bf16* __restrict__ res,
                             const float* __restrict__ pD,
                             const float* __restrict__ pUp,
                             const float* __restrict__ pCp,
                             const float* __restrict__ Av,
                             const float* __restrict__ Bv,
                             const float* __restrict__ Dv,
                             float* __restrict__ out)
{
    const int c = blockIdx.x, b = blockIdx.z;
    const int h0 = blockIdx.y * 512 + threadIdx.x * 2;
    float run0 = 0.f, run1 = 0.f;
    for (int cp = 0; cp < c; ++cp) {
        f32x2 v = *(const f32x2*)(pD + (b*NCH + cp)*H + h0);
        run0 += v[0]; run1 += v[1];
    }
    float uc0 = 0.f, uc1 = 0.f, cs0 = 0.f, cs1 = 0.f;
#pragma unroll
    for (int i = 0; i < 16; ++i) {
        f32x2 u = *(const f32x2*)(pUp + (b*16 + i)*H + h0);
        f32x2 s = *(const f32x2*)(pCp + (b*16 + i)*H + h0);
        uc0 += u[0]; uc1 += u[1]; cs0 += s[0]; cs1 += s[1];
    }
    const f32x2 a1 = *(const f32x2*)(Av + h0);
    const f32x2 b1 = *(const f32x2*)(Bv + h0);
    const float dd = Dv[0];
    size_t base = ((size_t)(b*LSEQ + c*LCH)) * H + h0;
    for (int l = 0; l < LCH; ++l) {
        size_t idx = base + (size_t)l * H;
        bf16x2 dv2 = *(const bf16x2*)(delta + idx);
        bf16x2 rs2 = *(const bf16x2*)(res + idx);
        float d0 = (float)dv2[0], d1v = (float)dv2[1];
        run0 += d0; run1 += d1v;
        f32x2 o;
        o[0] = __expf(d0*a1[0])*b1[0]*uc0 + run0*b1[0]*cs0 + (float)rs2[0]*dd;
        o[1] = __expf(d1v*a1[1])*b1[1]*uc1 + run1*b1[1]*cs1 + (float)rs2[1]*dd;
        *(f32x2*)(out + idx) = o;
    }
}

extern "C" void kernel_launch(void* const* d_in, const int* in_sizes, int n_in,
                              void* d_out, int out_size, void* d_ws, size_t ws_size,
                              hipStream_t stream)
{
    (void)in_sizes; (void)n_in; (void)out_size; (void)ws_size;
    const float* x  = (const float*)d_in[0];
    const float* Wp = (const float*)d_in[1];
    const float* Av = (const float*)d_in[2];
    const float* Bv = (const float*)d_in[3];
    const float* Dv = (const float*)d_in[4];
    const float* Wd = (const float*)d_in[5];
    const float* bd = (const float*)d_in[6];
    float* out = (float*)d_out;

    char* ws = (char*)d_ws;
    size_t o = 0;
    auto alloc = [&](size_t bytes) {
        void* p = ws + o; o += (bytes + 255) & ~(size_t)255; return p;
    };
    __bf16* xb   = (__bf16*)alloc((size_t)M_TOT * H * 2);
    __bf16* Wpb  = (__bf16*)alloc((size_t)3072 * H * 2);
    __bf16* Wdb  = (__bf16*)alloc((size_t)H * H * 2);
    __bf16* Wp1T = (__bf16*)alloc((size_t)H * H * 2);
    __bf16* resb = (__bf16*)alloc((size_t)M_TOT * H * 2);
    __bf16* db   = (__bf16*)alloc((size_t)M_TOT * H * 2);
    float*  pD   = (float*)alloc((size_t)BSZ * NCH * H * 4);
    float*  pUp  = (float*)alloc((size_t)64 * H * 4);
    float*  pCp  = (float*)alloc((size_t)64 * H * 4);

    cast_kernel<<<XB + PB + DB + TB, 256, 0, stream>>>(
        x, Wp, Wd, xb, Wpb, Wdb, Wp1T);
    // Wfuse = Wd @ Wp1  -> Wpb rows 0..1023
    gemm_bt<32, 0><<<dim3(8, 8), 256, 0, stream>>>(
        Wdb, Wp1T, Wpb, nullptr, nullptr, nullptr, nullptr, nullptr, nullptr);
    // Big GEMM: [8192,1024] @ [3072,1024]^T, 256^2 8-phase
    gemm256<<<dim3(384), 512, 0, stream>>>(
        xb, Wpb, db, resb, xb, bd, pD, pUp, pCp);
    final_kernel<<<dim3(NCH, 2, BSZ), 256, 0, stream>>>(db, resb, pD, pUp, pCp,
                                                        Av, Bv, Dv, out);
}

// Round 2
// 200.340 us; speedup vs baseline: 1.0284x; 1.0101x over previous
//
#include <hip/hip_runtime.h>
#include <hip/hip_bf16.h>
#include <cstdint>

#define H 1024
#define BSZ 4
#define LSEQ 2048
#define M_TOT (BSZ*LSEQ)   // 8192
#define NCH 32             // L-chunks for the delta scan
#define LCH (LSEQ/NCH)     // 64

typedef __attribute__((ext_vector_type(4))) float  f32x4;
typedef __attribute__((ext_vector_type(2))) float  f32x2;
typedef __attribute__((ext_vector_type(8))) __bf16 bf16x8;
typedef __attribute__((ext_vector_type(4))) __bf16 bf16x4;
typedef __attribute__((ext_vector_type(2))) __bf16 bf16x2;

typedef __attribute__((address_space(1))) unsigned int as1_u32;
typedef __attribute__((address_space(3))) unsigned int as3_u32;

__device__ __forceinline__ void gld_lds16(const void* g, const void* l) {
    as1_u32* gp = reinterpret_cast<as1_u32*>((uintptr_t)g);
    as3_u32* lp = reinterpret_cast<as3_u32*>((uint32_t)(uintptr_t)l);
    __builtin_amdgcn_global_load_lds(gp, lp, 16, 0, 0);
}

// fast softplus: stable, native exp/log (v_exp_f32/v_log_f32), ~8 instrs
__device__ __forceinline__ float softplus_fast(float f) {
    return fmaxf(f, 0.f) + __logf(1.f + __expf(-fabsf(f)));
}

// ---------------- small GEMM (Wfuse = Wd @ Wp1): unchanged 128x128 ----------
template<int KT, int MODE>
__global__ __launch_bounds__(256, 3) void gemm_bt(
    const __bf16* __restrict__ A,
    const __bf16* __restrict__ B,
    __bf16* __restrict__ O0)
{
    constexpr int K = KT * 32;
    __shared__ __align__(16) __bf16 lds[16384];

    const int tid  = threadIdx.x;
    const int lane = tid & 63;
    const int wid  = tid >> 6;
    const int wr   = (wid >> 1) * 64;
    const int wc   = (wid & 1) * 64;
    const int l15  = lane & 15;
    const int quad = lane >> 4;

    const int row0 = blockIdx.y * 128;
    const int col0 = blockIdx.x * 128;

    const int srow = lane >> 2;
    const int soct = (lane & 3) ^ ((lane >> 3) & 3);
    const __bf16* ag0 = A + (size_t)(row0 + (wid    )*16 + srow) * K + soct*8;
    const __bf16* ag1 = A + (size_t)(row0 + (wid + 4)*16 + srow) * K + soct*8;
    const __bf16* bg0 = B + (size_t)(col0 + (wid    )*16 + srow) * K + soct*8;
    const __bf16* bg1 = B + (size_t)(col0 + (wid + 4)*16 + srow) * K + soct*8;
    const int lA0 = (wid    )*512;
    const int lA1 = (wid + 4)*512;
    const int lB0 = 4096 + (wid    )*512;
    const int lB1 = 4096 + (wid + 4)*512;

    const int sw = (l15 >> 1) & 3;
    int aoff[4], boff[4];
#pragma unroll
    for (int i = 0; i < 4; ++i) {
        aoff[i] =        ((wr + i*16 + l15) * 4 + (quad ^ sw)) * 8;
        boff[i] = 4096 + ((wc + i*16 + l15) * 4 + (quad ^ sw)) * 8;
    }

    f32x4 acc[4][4] = {};

    auto stage = [&](int buf) {
        __bf16* base = lds + buf * 8192;
        gld_lds16(ag0, base + lA0);
        gld_lds16(ag1, base + lA1);
        gld_lds16(bg0, base + lB0);
        gld_lds16(bg1, base + lB1);
        ag0 += 32; ag1 += 32; bg0 += 32; bg1 += 32;
    };
    auto compute = [&](int buf) {
        const __bf16* base = lds + buf * 8192;
        bf16x8 af[4], bf[4];
#pragma unroll
        for (int i = 0; i < 4; ++i) af[i] = *(const bf16x8*)(base + aoff[i]);
#pragma unroll
        for (int j = 0; j < 4; ++j) bf[j] = *(const bf16x8*)(base + boff[j]);
#pragma unroll
        for (int i = 0; i < 4; ++i)
#pragma unroll
            for (int j = 0; j < 4; ++j)
                acc[i][j] = __builtin_amdgcn_mfma_f32_16x16x32_bf16(
                    af[i], bf[j], acc[i][j], 0, 0, 0);
    };

    stage(0);
#pragma unroll 2
    for (int kt = 0; kt < KT; ++kt) {
        __syncthreads();
        if (kt + 1 < KT) stage((kt + 1) & 1);
        compute(kt & 1);
    }

    const int colb = col0 + wc + l15;
    const int rowb = row0 + wr + quad*4;
#pragma unroll
    for (int i = 0; i < 4; ++i)
#pragma unroll
        for (int j = 0; j < 4; ++j) {
            const int col = colb + j*16;
#pragma unroll
            for (int r = 0; r < 4; ++r)
                O0[(size_t)(rowb + i*16 + r) * H + col] = (__bf16)acc[i][j][r];
        }
}

// ---------------- BIG GEMM: 256x128 tile, BK=64, 3-buffer, 768 blocks -------
// C[M,N] = A[M,K] @ B[N,K]^T, bf16, K=1024, 16 K-tiles.
// 768 blocks = exactly 3 rounds on 256 CUs (no tail quantization).
// LDS: 3 bufs x (A[256][64] + B[128][64]) bf16 = 144 KiB, 1 block/CU.
// 3-buffer rotation: tile t reads buf t%3; stages tile t+2 into buf (t+2)%3
//   (= buffer retired at t-1) -> staging NEVER touches a live buffer.
// Ledger (per-wave vmem ops, 6/tile): prologue stages t0,t1 (12 in flight);
//   each tile entry waits vmcnt(6) -> retires exactly the tile about to be
//   read, leaves next tile's 6 in flight (>= 1 full tile-time to land).
//   Tiles 14,15 peeled without staging (waits 6 then 0).
// Per tile: 2 phases x { 8x ds_read_b128 ; barrier ; 16 MFMA (setprio) }.
// XOR-granule swizzle via pre-swizzled global source + linear LDS dest.

#define BAR()    asm volatile("s_barrier" ::: "memory")
#define WAIT6()  asm volatile("s_waitcnt vmcnt(6)" ::: "memory")
#define WAIT0()  asm volatile("s_waitcnt vmcnt(0)" ::: "memory")

#define STA(b,u,kt) gld_lds16(Asrc + (size_t)((u)*64)*H + (kt)*64, \
                              lds + (b)*24576 + (u)*4096 + lwb)
#define STB(b,u,kt) gld_lds16(Bsrc + (size_t)((u)*64)*H + (kt)*64, \
                              lds + (b)*24576 + 16384 + (u)*4096 + lwb)
#define STAGE6(b,kt) do { STA(b,0,kt); STA(b,1,kt); STA(b,2,kt); STA(b,3,kt); \
                          STB(b,0,kt); STB(b,1,kt); } while(0)

#define TILE(bc,bn,kn,DS,WAITMAC) do {                                        \
    WAITMAC();                                                                \
    BAR();                                                                    \
    { const __bf16* base_ = lds + (bc)*24576;                                 \
      _Pragma("unroll")                                                       \
      for (int i_ = 0; i_ < 4; ++i_)                                          \
          af0[i_] = *(const bf16x8*)(base_ + aoff[i_]);                       \
      _Pragma("unroll")                                                       \
      for (int j_ = 0; j_ < 4; ++j_)                                          \
          bf0[j_] = *(const bf16x8*)(base_ + boff[j_]); }                     \
    if (DS) STAGE6(bn, kn);                                                   \
    BAR();                                                                    \
    __builtin_amdgcn_s_setprio(1);                                            \
    _Pragma("unroll")                                                         \
    for (int i_ = 0; i_ < 4; ++i_)                                            \
    _Pragma("unroll")                                                         \
    for (int j_ = 0; j_ < 4; ++j_)                                            \
        acc[i_][j_] = __builtin_amdgcn_mfma_f32_16x16x32_bf16(                \
            af0[i_], bf0[j_], acc[i_][j_], 0, 0, 0);                          \
    __builtin_amdgcn_s_setprio(0);                                            \
    BAR();                                                                    \
    { const __bf16* base_ = lds + (bc)*24576;                                 \
      _Pragma("unroll")                                                       \
      for (int i_ = 0; i_ < 4; ++i_)                                          \
          af1[i_] = *(const bf16x8*)(base_ + (aoff[i_] ^ 32));                \
      _Pragma("unroll")                                                       \
      for (int j_ = 0; j_ < 4; ++j_)                                          \
          bf1[j_] = *(const bf16x8*)(base_ + (boff[j_] ^ 32)); }              \
    BAR();                                                                    \
    __builtin_amdgcn_s_setprio(1);                                            \
    _Pragma("unroll")                                                         \
    for (int i_ = 0; i_ < 4; ++i_)                                            \
    _Pragma("unroll")                                                         \
    for (int j_ = 0; j_ < 4; ++j_)                                            \
        acc[i_][j_] = __builtin_amdgcn_mfma_f32_16x16x32_bf16(                \
            af1[i_], bf1[j_], acc[i_][j_], 0, 0, 0);                          \
    __builtin_amdgcn_s_setprio(0);                                            \
} while(0)

__global__ __launch_bounds__(512, 2) void gemm256b(
    const __bf16* __restrict__ A,
    const __bf16* __restrict__ B,
    __bf16* __restrict__ O0,
    __bf16* __restrict__ O2,
    const __bf16* __restrict__ xb,
    const float* __restrict__ bias,
    float* __restrict__ pD,
    float* __restrict__ pUp,    // [64][1024] partial sum(x*Cs) per 128-row blk
    float* __restrict__ pCp)    // [64][1024] partial sum(Cs)
{
    __shared__ __align__(16) __bf16 lds[73728];   // 144 KiB: 3 x (16K A + 8K B)

    const int tid  = threadIdx.x;
    const int lane = tid & 63;
    const int wid  = tid >> 6;
    const int l15  = lane & 15;
    const int quad = lane >> 4;
    const int wrv  = (wid >> 1) * 64;   // 4 M-strips of 64 rows
    const int wcv  = (wid & 1) * 64;    // 2 N-strips of 64 cols

    // XCD-bijective swizzle: 768 blocks, 768 % 8 == 0
    const int bid = blockIdx.x;
    const int swz = (bid & 7) * 96 + (bid >> 3);
    const int bx = swz % 24;            // 24 col-blocks of 128
    const int by = swz / 24;            // 32 row-blocks of 256
    const int row0 = by * 256;
    const int col0 = bx * 128;

    // staging: pre-swizzled global granule, linear LDS dest (rule 21)
    const int lg = (tid & 7) ^ ((tid >> 3) & 7);
    const __bf16* Asrc = A + (size_t)(row0 + (tid >> 3)) * H + lg * 8;
    const __bf16* Bsrc = B + (size_t)(col0 + (tid >> 3)) * H + lg * 8;
    const int lwb = wid * 512;          // wave-uniform LDS base (elements)

    int aoff[4], boff[4];
#pragma unroll
    for (int i = 0; i < 4; ++i)
        aoff[i] = (wrv + i*16 + l15)*64 + ((quad ^ (l15 & 7)) << 3);
#pragma unroll
    for (int j = 0; j < 4; ++j)
        boff[j] = 16384 + (wcv + j*16 + l15)*64 + ((quad ^ (l15 & 7)) << 3);

    f32x4 acc[4][4] = {};
    bf16x8 af0[4], bf0[4], af1[4], bf1[4];

    STAGE6(0, 0);
    STAGE6(1, 1);

#pragma unroll 1
    for (int g = 0; g < 4; ++g) {
        TILE(0, 2, 3*g + 2, 1, WAIT6);
        TILE(1, 0, 3*g + 3, 1, WAIT6);
        TILE(2, 1, 3*g + 4, 1, WAIT6);
    }
    TILE(0, 2, 14, 1, WAIT6);   // t12
    TILE(1, 0, 15, 1, WAIT6);   // t13
    TILE(2, 0,  0, 0, WAIT6);   // t14 (no stage)
    TILE(0, 0,  0, 0, WAIT0);   // t15 (no stage, drain)
    __syncthreads();

    // ---------------- epilogue ----------------
    const int seg   = col0 >> 10;
    const int cbase = col0 & 1023;
    const int colb  = cbase + wcv + l15;
    const int rowb  = row0 + wrv + quad*4;

    if (seg == 0) {
        // delta: bias + softplus + store + per-64-row-chunk col sums
        const int chunk = (row0 + wrv) >> 6;   // each M-strip = one chunk
#pragma unroll
        for (int j = 0; j < 4; ++j) {
            const int col = colb + j*16;
            const float bv = bias[col];
            float s = 0.f;
#pragma unroll
            for (int i = 0; i < 4; ++i)
#pragma unroll
                for (int r = 0; r < 4; ++r) {
                    float f = softplus_fast(acc[i][j][r] + bv);
                    O0[(size_t)(rowb + i*16 + r) * H + col] = (__bf16)f;
                    s += f;
                }
            s += __shfl_down(s, 32); s += __shfl_down(s, 16);
            if (quad == 0) pD[chunk*H + col] = s;  // single writer
        }
    } else if (seg == 2) {
        // residual: plain store
#pragma unroll
        for (int i = 0; i < 4; ++i)
#pragma unroll
            for (int j = 0; j < 4; ++j) {
                const int col = colb + j*16;
#pragma unroll
                for (int r = 0; r < 4; ++r)
                    O2[(size_t)(rowb + i*16 + r) * H + col] = (__bf16)acc[i][j][r];
            }
    } else {
        // Cs: 256x128 tile -> LDS (granule-XOR), coalesced reduce with xb,
        // cross-group reduce -> pUp/pCp[64][1024] (per-128-row partials).
#pragma unroll
        for (int i = 0; i < 4; ++i)
#pragma unroll
            for (int j = 0; j < 4; ++j) {
                const int lcol = wcv + j*16 + l15;
#pragma unroll
                for (int r = 0; r < 4; ++r) {
                    const int lrow = wrv + i*16 + quad*4 + r;
                    lds[lrow*128 + (((lcol>>3) ^ (lrow&15)) << 3) + (lcol&7)]
                        = (__bf16)acc[i][j][r];
                }
            }
        __syncthreads();
        const int g = tid >> 4, oct = tid & 15;     // 32 row-groups x 16 octs
        const int gc0 = cbase + oct*8;
        float su[8] = {}, sc[8] = {};
#pragma unroll
        for (int rr = 0; rr < 8; ++rr) {
            const int lrow = g*8 + rr;
            bf16x8 cv = *(const bf16x8*)(lds + lrow*128 +
                                         ((oct ^ (lrow&15)) << 3));
            bf16x8 xv = *(const bf16x8*)(xb + (size_t)(row0 + lrow)*H + gc0);
#pragma unroll
            for (int q = 0; q < 8; ++q) {
                float c = (float)cv[q];
                su[q] += (float)xv[q] * c;
                sc[q] += c;
            }
        }
        float* pf = reinterpret_cast<float*>(lds);
        __syncthreads();
#pragma unroll
        for (int q = 0; q < 8; ++q) {
            pf[g*128 + oct*8 + q]        = su[q];
            pf[4096 + g*128 + oct*8 + q] = sc[q];
        }
        __syncthreads();
        const int col = tid & 127;
        const int rb  = (tid >> 7) & 1;
        const int arr = tid >> 8;
        float s = 0.f;
#pragma unroll
        for (int g2 = 0; g2 < 16; ++g2)
            s += pf[arr*4096 + (rb*16 + g2)*128 + col];
        float* dst = arr ? pCp : pUp;
        dst[(size_t)((row0 >> 7) + rb)*H + cbase + col] = s;
    }
}

// ---- cast f32->bf16: x; pack W_proj segs {Cs,res}; Wd; transpose Wp1 -------
#define XB 8192
#define PB 2048
#define DB 1024
#define TB 256
__global__ void cast_kernel(const float* __restrict__ x,
                            const float* __restrict__ Wp,
                            const float* __restrict__ Wd,
                            __bf16* __restrict__ xb,
                            __bf16* __restrict__ Wpb,
                            __bf16* __restrict__ Wdb,
                            __bf16* __restrict__ Wp1T)
{
    __shared__ __bf16 tlds[64*65];
    const int t = threadIdx.x;
    const int bidx = blockIdx.x;

    if (bidx < XB + PB + DB) {
        const f32x4* src; __bf16* dst; int si, di;
        if (bidx < XB) {
            int i = bidx*256 + t;
            src = (const f32x4*)x;  si = i; dst = xb;  di = i;
        } else if (bidx < XB + PB) {
            int j = (bidx - XB)*256 + t;
            int row = j >> 8, cf = j & 255;
            src = (const f32x4*)Wp; si = (2048 + row)*256 + cf;
            dst = Wpb; di = (1024 + row)*256 + cf;
        } else {
            int j = (bidx - XB - PB)*256 + t;
            src = (const f32x4*)Wd; si = j; dst = Wdb; di = j;
        }
        f32x4 v = src[si];
        bf16x4 o = { (__bf16)v[0], (__bf16)v[1], (__bf16)v[2], (__bf16)v[3] };
        *(bf16x4*)(dst + (size_t)di*4) = o;
    } else {
        int tt = bidx - (XB + PB + DB);
        int ty = tt >> 4, tx = tt & 15;
        int rb = t >> 4, cb = t & 15;
#pragma unroll
        for (int rr = 0; rr < 4; ++rr) {
            int row = rb*4 + rr;
            f32x4 v = *(const f32x4*)(Wp + (size_t)(ty*64 + row)*1024 + tx*64 + cb*4);
#pragma unroll
            for (int q = 0; q < 4; ++q)
                tlds[row*65 + cb*4 + q] = (__bf16)v[q];
        }
        __syncthreads();
#pragma unroll
        for (int rr = 0; rr < 4; ++rr) {
            int kk = rb*4 + rr;
            bf16x4 o = { tlds[(cb*4+0)*65 + kk], tlds[(cb*4+1)*65 + kk],
                         tlds[(cb*4+2)*65 + kk], tlds[(cb*4+3)*65 + kk] };
            *(bf16x4*)(Wp1T + (size_t)(tx*64 + kk)*1024 + ty*64 + cb*4) = o;
        }
    }
}

// ---- final: inline chunk-prefix + partial-sum gather + elementwise combine --
// y = exp(d*A1)*B1*uC + B1*cumsum(d)*Csum + res*D
// grid (NCH, 4, BSZ) x 128 thr: finer split for latency hiding (512 blocks).
__global__ void final_kernel(const __bf16* __restrict__ delta,
                             const __bf16* __restrict__ res,
                             const float* __restrict__ pD,   // [128][1024]
                             const float* __restrict__ pUp,  // [64][1024]
                             const float* __restrict__ pCp,  // [64][1024]
                             const float* __restrict__ Av,
                             const float* __restrict__ Bv,
                             const float* __restrict__ Dv,
                             float* __restrict__ out)
{
    const int c = blockIdx.x, b = blockIdx.z;
    const int h0 = blockIdx.y * 256 + threadIdx.x * 2;
    float run0 = 0.f, run1 = 0.f;
    for (int cp = 0; cp < c; ++cp) {
        f32x2 v = *(const f32x2*)(pD + (b*NCH + cp)*H + h0);
        run0 += v[0]; run1 += v[1];
    }
    float uc0 = 0.f, uc1 = 0.f, cs0 = 0.f, cs1 = 0.f;
#pragma unroll
    for (int i = 0; i < 16; ++i) {
        f32x2 u = *(const f32x2*)(pUp + (b*16 + i)*H + h0);
        f32x2 s = *(const f32x2*)(pCp + (b*16 + i)*H + h0);
        uc0 += u[0]; uc1 += u[1]; cs0 += s[0]; cs1 += s[1];
    }
    const f32x2 a1 = *(const f32x2*)(Av + h0);
    const f32x2 b1 = *(const f32x2*)(Bv + h0);
    const float dd = Dv[0];
    size_t base = ((size_t)(b*LSEQ + c*LCH)) * H + h0;
    for (int l = 0; l < LCH; ++l) {
        size_t idx = base + (size_t)l * H;
        bf16x2 dv2 = *(const bf16x2*)(delta + idx);
        bf16x2 rs2 = *(const bf16x2*)(res + idx);
        float d0 = (float)dv2[0], d1v = (float)dv2[1];
        run0 += d0; run1 += d1v;
        f32x2 o;
        o[0] = __expf(d0*a1[0])*b1[0]*uc0 + run0*b1[0]*cs0 + (float)rs2[0]*dd;
        o[1] = __expf(d1v*a1[1])*b1[1]*uc1 + run1*b1[1]*cs1 + (float)rs2[1]*dd;
        *(f32x2*)(out + idx) = o;
    }
}

extern "C" void kernel_launch(void* const* d_in, const int* in_sizes, int n_in,
                              void* d_out, int out_size, void* d_ws, size_t ws_size,
                              hipStream_t stream)
{
    (void)in_sizes; (void)n_in; (void)out_size; (void)ws_size;
    const float* x  = (const float*)d_in[0];
    const float* Wp = (const float*)d_in[1];
    const float* Av = (const float*)d_in[2];
    const float* Bv = (const float*)d_in[3];
    const float* Dv = (const float*)d_in[4];
    const float* Wd = (const float*)d_in[5];
    const float* bd = (const float*)d_in[6];
    float* out = (float*)d_out;

    char* ws = (char*)d_ws;
    size_t o = 0;
    auto alloc = [&](size_t bytes) {
        void* p = ws + o; o += (bytes + 255) & ~(size_t)255; return p;
    };
    __bf16* xb   = (__bf16*)alloc((size_t)M_TOT * H * 2);
    __bf16* Wpb  = (__bf16*)alloc((size_t)3072 * H * 2);
    __bf16* Wdb  = (__bf16*)alloc((size_t)H * H * 2);
    __bf16* Wp1T = (__bf16*)alloc((size_t)H * H * 2);
    __bf16* resb = (__bf16*)alloc((size_t)M_TOT * H * 2);
    __bf16* db   = (__bf16*)alloc((size_t)M_TOT * H * 2);
    float*  pD   = (float*)alloc((size_t)BSZ * NCH * H * 4);
    float*  pUp  = (float*)alloc((size_t)64 * H * 4);
    float*  pCp  = (float*)alloc((size_t)64 * H * 4);

    cast_kernel<<<XB + PB + DB + TB, 256, 0, stream>>>(
        x, Wp, Wd, xb, Wpb, Wdb, Wp1T);
    // Wfuse = Wd @ Wp1  -> Wpb rows 0..1023
    gemm_bt<32, 0><<<dim3(8, 8), 256, 0, stream>>>(Wdb, Wp1T, Wpb);
    // Big GEMM: [8192,1024] @ [3072,1024]^T, 256x128 3-buffer, 768 blocks
    gemm256b<<<dim3(768), 512, 0, stream>>>(
        xb, Wpb, db, resb, xb, bd, pD, pUp, pCp);
    final_kernel<<<dim3(NCH, 4, BSZ), 128, 0, stream>>>(db, resb, pD, pUp, pCp,
                                                        Av, Bv, Dv, out);
}